// Round 4
// baseline (180.741 us; speedup 1.0000x reference)
//
#include <hip/hip_runtime.h>
#include <hip/hip_bf16.h>
#include <math.h>

#define NB 64
#define HH 512
#define WW 512
#define KK 31
#define PP 15
#define NSTRIP 16
#define SROWS (HH / NSTRIP)     // 32 rows per strip
#define NROWS (NB * HH)         // 32768 rows total
#define ROWS_PER_WAVE 8

// ws layout (fast path):
//   part[0..1023]    = per-block inter
//   part[1024..2047] = per-block union
//   H  (at byte offset 8192): 64 MB horizontal box-sum field
#define WS_NEED (8192 + (size_t)NROWS * WW * 4)

// ---------------- Pass 1: H(r,x) = sum_{c=x-15..x+15} mask[r][c] (zero-pad) ---------------
__global__ __launch_bounds__(256) void hrow_kernel(const float* __restrict__ mask,
                                                   float* __restrict__ H) {
    const int gw   = (blockIdx.x * 256 + threadIdx.x) >> 6;   // global wave id, 0..4095
    const int lane = threadIdx.x & 63;

    for (int k = 0; k < ROWS_PER_WAVE; ++k) {
        const size_t r = (size_t)gw * ROWS_PER_WAVE + k;
        const float* row = mask + r * WW;
        const int xbase = lane * 8;
        const float4 a = *(const float4*)(row + xbase);
        const float4 b = *(const float4*)(row + xbase + 4);

        // in-lane inclusive prefix of 8 elements
        float s0 = a.x;
        float s1 = s0 + a.y;
        float s2 = s1 + a.z;
        float s3 = s2 + a.w;
        float s4 = s3 + b.x;
        float s5 = s4 + b.y;
        float s6 = s5 + b.z;
        float s7 = s6 + b.w;

        // wave-inclusive scan of lane totals
        float incl = s7;
        #pragma unroll
        for (int off = 1; off < 64; off <<= 1) {
            float t = __shfl_up(incl, off);
            if (lane >= off) incl += t;
        }
        const float base = incl - s7;          // exclusive prefix
        s0 += base; s1 += base; s2 += base; s3 += base;
        s4 += base; s5 += base; s6 += base; s7 += base;
        // now s_j = M[8*lane + j] (inclusive row prefix)

        const float total = __shfl(incl, 63);  // M[511]

        // hi taps: M[x+15].  x=8l+j: j=0 -> lane+1 elem7; j>=1 -> lane+2 elem j-1
        float hi0 = __shfl_down(s7, 1);
        float hi1 = __shfl_down(s0, 2);
        float hi2 = __shfl_down(s1, 2);
        float hi3 = __shfl_down(s2, 2);
        float hi4 = __shfl_down(s3, 2);
        float hi5 = __shfl_down(s4, 2);
        float hi6 = __shfl_down(s5, 2);
        float hi7 = __shfl_down(s6, 2);
        // lo taps: M[x-16] -> lane-2 elem j
        float lo0 = __shfl_up(s0, 2);
        float lo1 = __shfl_up(s1, 2);
        float lo2 = __shfl_up(s2, 2);
        float lo3 = __shfl_up(s3, 2);
        float lo4 = __shfl_up(s4, 2);
        float lo5 = __shfl_up(s5, 2);
        float lo6 = __shfl_up(s6, 2);
        float lo7 = __shfl_up(s7, 2);

        float h[8];
        const float hiv[8] = {hi0, hi1, hi2, hi3, hi4, hi5, hi6, hi7};
        const float lov[8] = {lo0, lo1, lo2, lo3, lo4, lo5, lo6, lo7};
        #pragma unroll
        for (int j = 0; j < 8; ++j) {
            const int x = xbase + j;
            const float mhi = (x + PP > WW - 1) ? total : hiv[j];
            const float mlo = (x - PP - 1 >= 0) ? lov[j] : 0.0f;
            h[j] = mhi - mlo;
        }

        float* orow = H + r * WW;
        *(float4*)(orow + xbase)     = make_float4(h[0], h[1], h[2], h[3]);
        *(float4*)(orow + xbase + 4) = make_float4(h[4], h[5], h[6], h[7]);
    }
}

// ---------------- Pass 2: running vertical 31-sum of H + fused epilogue ---------------
__global__ __launch_bounds__(512) void dice_kernel(
        const float* __restrict__ pred,
        const float* __restrict__ mask,
        const float* __restrict__ H,
        float* __restrict__ part) {
    const int strip = blockIdx.x;
    const int b     = blockIdx.y;
    const int x     = threadIdx.x;
    const int wave  = x >> 6;
    const int lane  = x & 63;

    __shared__ float red[16];

    const float* Hb = H    + (size_t)b * HH * WW;
    const float* mb = mask + (size_t)b * HH * WW;
    const float* pb = pred + (size_t)b * HH * WW;
    const int y0 = strip * SROWS;

    // init: B = sum_{r=y0-15}^{y0+14} H[r][x] (rows clamped)
    float B = 0.0f;
    {
        const int rlo = (y0 - PP < 0) ? 0 : y0 - PP;
        const int rhi = y0 + PP - 1;            // always < HH
        for (int r = rlo; r <= rhi; ++r) B += Hb[r * WW + x];
    }

    float inter = 0.0f, uni = 0.0f;
    #pragma unroll 4
    for (int i = 0; i < SROWS; ++i) {
        const int y = y0 + i;
        const float he = (y + PP < HH) ? Hb[(y + PP) * WW + x] : 0.0f;
        const float hl = (y - PP >= 0) ? Hb[(y - PP) * WW + x] : 0.0f;
        const float m  = mb[y * WW + x];
        const float p  = pb[y * WW + x];
        B += he;                                // window [y-15, y+15]
        const float avg = B * (1.0f / (float)(KK * KK));
        const float w   = 1.0f + 5.0f * fabsf(avg - m);
        const float sg  = 1.0f / (1.0f + __expf(-p));
        inter += sg * m * w;
        uni   += (sg + m) * w;
        B -= hl;                                // advance to next row's lower edge
    }

    #pragma unroll
    for (int off = 32; off > 0; off >>= 1) {
        inter += __shfl_down(inter, off);
        uni   += __shfl_down(uni, off);
    }
    if (lane == 0) { red[wave] = inter; red[8 + wave] = uni; }
    __syncthreads();
    if (x == 0) {
        float ti = 0.0f, tu = 0.0f;
        #pragma unroll
        for (int w2 = 0; w2 < 8; ++w2) { ti += red[w2]; tu += red[8 + w2]; }
        const int bid = b * NSTRIP + strip;
        part[bid] = ti;
        part[NB * NSTRIP + bid] = tu;
    }
}

// ---------------- Fallback (round-3 monolithic kernel) if ws too small ---------------
#define RPB 4
#define NROUND (SROWS / RPB)
#define PSTR 544

__global__ __launch_bounds__(512, 8) void dice_strip_kernel(
        const float* __restrict__ pred,
        const float* __restrict__ mask,
        float* __restrict__ part) {
    const int strip = blockIdx.x;
    const int b     = blockIdx.y;
    const int x     = threadIdx.x;
    const int wave  = x >> 6;
    const int lane  = x & 63;

    __shared__ float wtot[RPB * 8];
    __shared__ float Pbuf[RPB * PSTR];
    __shared__ float red[16];

    const float* mbase = mask + (size_t)b * HH * WW;
    const float* pbase = pred + (size_t)b * HH * WW;
    const int y0 = strip * SROWS;

    if (x < 16) {
        #pragma unroll
        for (int r = 0; r < RPB; ++r) Pbuf[r * PSTR + x] = 0.0f;
    }

    float vcarry = 0.0f;
    {
        const int rlo = (y0 - PP - 1 < 0) ? 0 : y0 - PP - 1;
        const int rhi = (y0 + PP - 1 > HH - 1) ? HH - 1 : y0 + PP - 1;
        for (int r = rlo; r <= rhi; ++r) vcarry += mbase[r * WW + x];
    }

    float inter = 0.0f, uni = 0.0f;

    for (int j = 0; j < NROUND; ++j) {
        const int y = y0 + j * RPB;
        float en[RPB], lv[RPB], mc[RPB], pv[RPB];
        #pragma unroll
        for (int r = 0; r < RPB; ++r) {
            const int ra = y + r + PP;
            const int rs = y + r - PP - 1;
            en[r] = (ra < HH) ? mbase[ra * WW + x] : 0.0f;
            lv[r] = (rs >= 0) ? mbase[rs * WW + x] : 0.0f;
            mc[r] = mbase[(y + r) * WW + x];
            pv[r] = pbase[(y + r) * WW + x];
        }
        float incl[RPB];
        {
            float run = vcarry;
            #pragma unroll
            for (int r = 0; r < RPB; ++r) { run += en[r] - lv[r]; incl[r] = run; }
            vcarry = run;
        }
        #pragma unroll
        for (int off = 1; off < 64; off <<= 1) {
            float t[RPB];
            #pragma unroll
            for (int r = 0; r < RPB; ++r) t[r] = __shfl_up(incl[r], off);
            #pragma unroll
            for (int r = 0; r < RPB; ++r) if (lane >= off) incl[r] += t[r];
        }
        if (lane == 63) {
            #pragma unroll
            for (int r = 0; r < RPB; ++r) wtot[r * 8 + wave] = incl[r];
        }
        __syncthreads();
        float bm[RPB];
        #pragma unroll
        for (int r = 0; r < RPB; ++r) bm[r] = (lane < wave) ? wtot[r * 8 + lane] : 0.0f;
        #pragma unroll
        for (int off = 1; off < 64; off <<= 1) {
            #pragma unroll
            for (int r = 0; r < RPB; ++r) bm[r] += __shfl_xor(bm[r], off);
        }
        #pragma unroll
        for (int r = 0; r < RPB; ++r) Pbuf[r * PSTR + 16 + x] = bm[r] + incl[r];
        if (wave == 7) {
            #pragma unroll
            for (int r = 0; r < RPB; ++r) {
                const float p511 = bm[r] + wtot[r * 8 + 7];
                if (lane >= 48) Pbuf[r * PSTR + 528 + (lane - 48)] = p511;
            }
        }
        __syncthreads();
        #pragma unroll
        for (int r = 0; r < RPB; ++r) {
            const float hsum = Pbuf[r * PSTR + 16 + x + PP] - Pbuf[r * PSTR + x];
            const float avg  = hsum * (1.0f / (float)(KK * KK));
            const float m    = mc[r];
            const float w    = 1.0f + 5.0f * fabsf(avg - m);
            const float sg   = 1.0f / (1.0f + __expf(-pv[r]));
            inter += sg * m * w;
            uni   += (sg + m) * w;
        }
    }

    #pragma unroll
    for (int off = 32; off > 0; off >>= 1) {
        inter += __shfl_down(inter, off);
        uni   += __shfl_down(uni, off);
    }
    if (lane == 0) { red[wave] = inter; red[8 + wave] = uni; }
    __syncthreads();
    if (x == 0) {
        float ti = 0.0f, tu = 0.0f;
        #pragma unroll
        for (int w2 = 0; w2 < 8; ++w2) { ti += red[w2]; tu += red[8 + w2]; }
        const int bid = b * NSTRIP + strip;
        part[bid] = ti;
        part[NB * NSTRIP + bid] = tu;
    }
}

__global__ void dice_final_kernel(const float* __restrict__ part,
                                  float* __restrict__ out) {
    const int t = threadIdx.x;  // 64 threads, one per image
    float inter = 0.0f, uni = 0.0f;
    #pragma unroll
    for (int s = 0; s < NSTRIP; ++s) {
        inter += part[t * NSTRIP + s];
        uni   += part[NB * NSTRIP + t * NSTRIP + s];
    }
    float wd = 1.0f - (2.0f * inter + 0.5f) / (uni + 0.5f);
    #pragma unroll
    for (int off = 32; off > 0; off >>= 1) wd += __shfl_down(wd, off);
    if (t == 0) out[0] = wd * (1.0f / (float)NB);
}

extern "C" void kernel_launch(void* const* d_in, const int* in_sizes, int n_in,
                              void* d_out, int out_size, void* d_ws, size_t ws_size,
                              hipStream_t stream) {
    const float* pred = (const float*)d_in[0];
    const float* mask = (const float*)d_in[1];
    float* out  = (float*)d_out;
    float* part = (float*)d_ws;                       // 2048 floats
    float* H    = (float*)((char*)d_ws + 8192);       // 64 MB

    dim3 grid2(NSTRIP, NB);                           // 1024 blocks
    if (ws_size >= WS_NEED) {
        hrow_kernel<<<1024, 256, 0, stream>>>(mask, H);
        dice_kernel<<<grid2, 512, 0, stream>>>(pred, mask, H, part);
    } else {
        dice_strip_kernel<<<grid2, 512, 0, stream>>>(pred, mask, part);
    }
    dice_final_kernel<<<1, 64, 0, stream>>>(part, out);
}